// Round 7
// baseline (1676.121 us; speedup 1.0000x reference)
//
#include <hip/hip_runtime.h>

// ---------------- problem constants ----------------
#define T_TOK 4096      // B*S tokens
#define HDIM  2880
#define IDIM  2880
#define NEXP  8
#define TOPK  4
#define WEL   (2880 * 2880)   // elems per weight matrix

// GEMM tiling: 256x96 block tile, BK=64, 8 waves (4x2) of 64x48, 512 threads.
// LDS tiles LINEAR [row][64] bf16 (128B rows), XOR-swizzled on the 16B k-slot:
//   physical_slot = logical_slot ^ (row & 7)
// global_load_lds writes lane l -> base + l*16 (linear); per-lane GLOBAL source
// is pre-swizzled so swizzled reads see logical order (both-sides involution).
// Double-buffered with raw s_barrier + counted vmcnt:
//   stage(next); s_waitcnt vmcnt(Nw); s_barrier; compute(cur); s_barrier
#define BM 256
#define BN 96
#define BK 64
#define NPAN 30         // 2880 / 96 output n-panels
#define ASZ (BM * BK)   // 16384 elems / 32 KB per buffer half
#define BSZ (BN * BK)   // 6144 elems / 12 KB per buffer half
#define NSTEP 45        // 2880 / 64

typedef __attribute__((ext_vector_type(8))) short  s16x8;
typedef __attribute__((ext_vector_type(8))) unsigned short u16x8;
typedef __attribute__((ext_vector_type(4))) float  f32x4;

__device__ __forceinline__ unsigned short f2bf(float f) {
  unsigned int u = __float_as_uint(f);
  u += 0x7FFFu + ((u >> 16) & 1u);
  return (unsigned short)(u >> 16);
}

__device__ __forceinline__ void gload16(const unsigned short* g, unsigned short* l) {
  __builtin_amdgcn_global_load_lds(
      (const __attribute__((address_space(1))) void*)g,
      (__attribute__((address_space(3))) void*)l, 16, 0, 0);
}

// bijective XCD-aware block swizzle (m204): XCD x gets a contiguous work chunk
__device__ __forceinline__ int xcd_swz(int orig, int n) {
  int q = n >> 3, r = n & 7;
  int x = orig & 7, idx = orig >> 3;
  return (x < r ? x * (q + 1) : r * (q + 1) + (x - r) * q) + idx;
}

// ---------------- x f32 -> bf16 ----------------
__global__ __launch_bounds__(256) void cvt_kernel(const float* __restrict__ x,
                                                  unsigned short* __restrict__ xb) {
  int i = blockIdx.x * 256 + threadIdx.x;
  const f32x4* p = (const f32x4*)x;
  f32x4 a = p[2 * (size_t)i];
  f32x4 b = p[2 * (size_t)i + 1];
  u16x8 o;
  o[0] = f2bf(a[0]); o[1] = f2bf(a[1]); o[2] = f2bf(a[2]); o[3] = f2bf(a[3]);
  o[4] = f2bf(b[0]); o[5] = f2bf(b[1]); o[6] = f2bf(b[2]); o[7] = f2bf(b[3]);
  *(u16x8*)(xb + (size_t)i * 8) = o;
}

// ---------------- weight transpose+convert for a group of G experts ----------------
__global__ __launch_bounds__(256) void transpose_group_kernel(
    const float* __restrict__ wg, const float* __restrict__ wu,
    const float* __restrict__ wd, unsigned short* __restrict__ wbuf, int ge) {
  __shared__ unsigned short st[64][72];
  const int z = blockIdx.z, j = z / 3, m = z % 3;
  const float* src = (m == 0 ? wg : (m == 1 ? wu : wd)) + (size_t)(ge + j) * WEL;
  unsigned short* dst = wbuf + (size_t)(j * 3 + m) * WEL;
  const int k0 = blockIdx.x * 64, n0 = blockIdx.y * 64;
  const int tid = threadIdx.x;
#pragma unroll
  for (int u = 0; u < 4; ++u) {
    int idx = tid + u * 256;
    int kr = idx >> 4;
    int nc = (idx & 15) * 4;
    f32x4 v = *(const f32x4*)(src + (size_t)(k0 + kr) * 2880 + (n0 + nc));
#pragma unroll
    for (int q = 0; q < 4; ++q) st[nc + q][kr] = f2bf(v[q]);
  }
  __syncthreads();
  int n = tid >> 2;
  int kc = (tid & 3) * 16;
  u16x8 a = *(const u16x8*)(&st[n][kc]);
  u16x8 b = *(const u16x8*)(&st[n][kc + 8]);
  unsigned short* po = dst + (size_t)(n0 + n) * 2880 + (k0 + kc);
  *(u16x8*)(po) = a;
  *(u16x8*)(po + 8) = b;
}

// ---------------- router: 4 tokens/wave, butterfly reduce ----------------
__global__ __launch_bounds__(256) void router_kernel(const float* __restrict__ x,
                                                     const float* __restrict__ rw,
                                                     const float* __restrict__ rb,
                                                     float* __restrict__ aff,
                                                     int* __restrict__ cnt,
                                                     int* __restrict__ lst) {
  const int wv = threadIdx.x >> 6, lane = threadIdx.x & 63;
  const int tok0 = (blockIdx.x * 4 + wv) * 4;
  float acc[4][NEXP];
#pragma unroll
  for (int t = 0; t < 4; ++t)
#pragma unroll
    for (int e = 0; e < NEXP; ++e) acc[t][e] = 0.f;

#pragma unroll
  for (int it = 0; it < 12; ++it) {
    int c = it * 64 + lane;
    if (c < 720) {
      f32x4 w4[NEXP];
#pragma unroll
      for (int e = 0; e < NEXP; ++e)
        w4[e] = *(const f32x4*)(rw + (size_t)e * HDIM + c * 4);
#pragma unroll
      for (int t = 0; t < 4; ++t) {
        f32x4 xv = *(const f32x4*)(x + (size_t)(tok0 + t) * HDIM + c * 4);
#pragma unroll
        for (int e = 0; e < NEXP; ++e)
          acc[t][e] += xv[0] * w4[e][0] + xv[1] * w4[e][1] + xv[2] * w4[e][2] + xv[3] * w4[e][3];
      }
    }
  }
#pragma unroll
  for (int t = 0; t < 4; ++t)
#pragma unroll
    for (int e = 0; e < NEXP; ++e) {
#pragma unroll
      for (int m = 32; m; m >>= 1) acc[t][e] += __shfl_xor(acc[t][e], m);
    }
  if (lane < 4) {
    int tok = tok0 + lane;
    float lg[NEXP];
#pragma unroll
    for (int e = 0; e < NEXP; ++e) lg[e] = acc[lane][e] + rb[e];
    bool used[NEXP];
#pragma unroll
    for (int e = 0; e < NEXP; ++e) used[e] = false;
    int bi[TOPK]; float bv[TOPK];
#pragma unroll
    for (int s = 0; s < TOPK; ++s) {
      int best = 0; float vbest = -1e30f;
#pragma unroll
      for (int e = 0; e < NEXP; ++e)
        if (!used[e] && lg[e] > vbest) { vbest = lg[e]; best = e; }
      used[best] = true; bi[s] = best; bv[s] = vbest;
    }
    float mx = bv[0];
    float w[TOPK]; float ssum = 0.f;
#pragma unroll
    for (int s = 0; s < TOPK; ++s) { w[s] = __expf(bv[s] - mx); ssum += w[s]; }
    float o[NEXP];
#pragma unroll
    for (int e = 0; e < NEXP; ++e) o[e] = 0.f;
#pragma unroll
    for (int s = 0; s < TOPK; ++s) o[bi[s]] = w[s] / ssum;
#pragma unroll
    for (int e = 0; e < NEXP; ++e) aff[(size_t)tok * NEXP + e] = o[e];
#pragma unroll
    for (int s = 0; s < TOPK; ++s) {
      int p = atomicAdd(&cnt[bi[s]], 1);
      lst[bi[s] * T_TOK + p] = tok;
    }
  }
}

// ---------------- sched: per-expert block prefixes + slot prefixes ----------------
__global__ void sched_kernel(const int* __restrict__ cnt, int* __restrict__ gbs,
                             int* __restrict__ ess, int* __restrict__ gtot, int G) {
  if (threadIdx.x == 0 && blockIdx.x == 0) {
    int ng = NEXP / G;
    for (int g = 0; g < ng; ++g) {
      int b = 0, s = 0;
      for (int j = 0; j < G; ++j) {
        int e = g * G + j;
        gbs[e] = b; ess[e] = s;
        b += ((cnt[e] + BM - 1) / BM) * NPAN;
        s += cnt[e];
      }
      gtot[g] = b;
    }
  }
}

// locate (expert, m0, n0) from swizzled 1D block id; expert-major, n-outer, m-inner
__device__ __forceinline__ bool locate(int bx, const int* gbs, const int* cnts,
                                       int ge, int G, const int* gtot_g,
                                       int& e, int& m0, int& n0, int& cnt) {
  if (bx >= *gtot_g) return false;
  int j = 0;
  for (int t = 1; t < G; ++t) j += (bx >= gbs[ge + t]) ? 1 : 0;
  e = ge + j;
  cnt = cnts[e];
  int mb = (cnt + BM - 1) >> 8;
  int local = bx - gbs[e];
  int nIdx = local / mb;
  int mIdx = local - nIdx * mb;
  m0 = mIdx * BM;
  n0 = nIdx * BN;
  return true;
}

// ---------------- gate/up fused GEMM + SwiGLU + affinity -> h4 (per-slot rows) ----------
__global__ __launch_bounds__(512) void gateup_kernel(
    const unsigned short* __restrict__ xb, const unsigned short* __restrict__ wbuf,
    const float* __restrict__ aff, const int* __restrict__ lst,
    const int* __restrict__ cnts, const int* __restrict__ gbs,
    const int* __restrict__ ess, const int* __restrict__ gtot_g,
    unsigned short* __restrict__ h4, int ge, int G) {
  int e, m0, n0, cnt;
  const int bx = xcd_swz(blockIdx.x, gridDim.x);
  if (!locate(bx, gbs, cnts, ge, G, gtot_g, e, m0, n0, cnt)) return;
  const int j = e - ge;
  const int slotbase = ess[e];
  const unsigned short* wgt = wbuf + (size_t)j * 3 * WEL;
  const unsigned short* wut = wgt + WEL;

  __shared__ __align__(16) unsigned short Al[2 * ASZ];    // 64KB dbuf
  __shared__ __align__(16) unsigned short Bgl[2 * BSZ];   // 24KB
  __shared__ __align__(16) unsigned short Bul[2 * BSZ];   // 24KB

  const int tid = threadIdx.x;
  const int wv = tid >> 6, lane = tid & 63;
  const int msub = (wv >> 1) * 64, nsub = (wv & 1) * 48;
  const int l15 = lane & 15, l4 = lane >> 4;
  const int lr = lane >> 3, lc = lane & 7;
  const int* mylst = lst + e * T_TOK;

  // A: 32 segments of (8 rows x 8 slots); wave wv stages segs wv+8u
  const unsigned short* asrc[4]; unsigned short* adst[4];
#pragma unroll
  for (int u = 0; u < 4; ++u) {
    int s = wv + 8 * u;
    int r = s * 8 + lr;
    int tok = mylst[min(m0 + r, cnt - 1)];
    asrc[u] = xb + (size_t)tok * HDIM + (lc ^ (r & 7)) * 8;
    adst[u] = &Al[s * 512];
  }
  // B: 12 segs each; uniform 7 loads/wave:
  //   wv<4 : Bg {wv, 8+wv}, Bu {wv}
  //   wv>=4: Bg {wv},       Bu {wv, 4+wv}
  const int sBx = (wv < 4) ? (8 + wv) : (4 + wv);   // extra seg id
  const unsigned short* bgsrc0; const unsigned short* busrc0; const unsigned short* bxsrc;
  unsigned short* bgdst0; unsigned short* budst0; unsigned short* bxdst;
  {
    int r0 = wv * 8 + lr;
    size_t o0 = (size_t)(n0 + r0) * HDIM + (size_t)((lc ^ (r0 & 7)) * 8);
    bgsrc0 = wgt + o0; bgdst0 = &Bgl[wv * 512];
    busrc0 = wut + o0; budst0 = &Bul[wv * 512];
    int rx = sBx * 8 + lr;
    size_t ox = (size_t)(n0 + rx) * HDIM + (size_t)((lc ^ (rx & 7)) * 8);
    bxsrc = (wv < 4) ? (wgt + ox) : (wut + ox);
    bxdst = (wv < 4) ? &Bgl[sBx * 512] : &Bul[sBx * 512];
  }

  f32x4 accg[4][3]; f32x4 accu[4][3];
#pragma unroll
  for (int mf = 0; mf < 4; ++mf)
#pragma unroll
    for (int nf = 0; nf < 3; ++nf) { accg[mf][nf] = (f32x4)0.f; accu[mf][nf] = (f32x4)0.f; }

  auto stage = [&](int buf, int k0) {   // 7 VMEM ops per wave, uniform
    int ao = buf * ASZ, bo = buf * BSZ;
#pragma unroll
    for (int u = 0; u < 4; ++u) gload16(asrc[u] + k0, adst[u] + ao);
    gload16(bgsrc0 + k0, bgdst0 + bo);
    gload16(busrc0 + k0, budst0 + bo);
    gload16(bxsrc + k0, bxdst + bo);
  };
  auto compute = [&](int buf) {
    const unsigned short* Ab = Al + buf * ASZ;
    const unsigned short* Bg = Bgl + buf * BSZ;
    const unsigned short* Bu = Bul + buf * BSZ;
#pragma unroll
    for (int kk = 0; kk < 2; ++kk) {
      s16x8 af[4];
#pragma unroll
      for (int mf = 0; mf < 4; ++mf) {
        int R = msub + mf * 16 + l15;
        int sl = (kk * 4 + l4) ^ (R & 7);
        af[mf] = *(const s16x8*)(&Ab[R * 64 + sl * 8]);
      }
#pragma unroll
      for (int nf = 0; nf < 3; ++nf) {
        int R = nsub + nf * 16 + l15;
        int sl = (kk * 4 + l4) ^ (R & 7);
        s16x8 bg = *(const s16x8*)(&Bg[R * 64 + sl * 8]);
        s16x8 bu = *(const s16x8*)(&Bu[R * 64 + sl * 8]);
#pragma unroll
        for (int mf = 0; mf < 4; ++mf) {
          accg[mf][nf] = __builtin_amdgcn_mfma_f32_16x16x32_bf16(af[mf], bg, accg[mf][nf], 0, 0, 0);
          accu[mf][nf] = __builtin_amdgcn_mfma_f32_16x16x32_bf16(af[mf], bu, accu[mf][nf], 0, 0, 0);
        }
      }
    }
  };

  stage(0, 0);
#pragma unroll 1
  for (int t = 0; t < NSTEP - 1; t += 2) {
    stage(1, (t + 1) * BK);
    asm volatile("s_waitcnt vmcnt(7)" ::: "memory");
    __builtin_amdgcn_s_barrier();
    compute(0);
    __builtin_amdgcn_s_barrier();
    stage(0, (t + 2) * BK);
    asm volatile("s_waitcnt vmcnt(7)" ::: "memory");
    __builtin_amdgcn_s_barrier();
    compute(1);
    __builtin_amdgcn_s_barrier();
  }
  asm volatile("s_waitcnt vmcnt(0)" ::: "memory");
  __builtin_amdgcn_s_barrier();
  compute(0);   // tile 44 lives in buf 0

#pragma unroll
  for (int mf = 0; mf < 4; ++mf)
#pragma unroll
    for (int r = 0; r < 4; ++r) {
      int slot = m0 + msub + mf * 16 + l4 * 4 + r;
      if (slot < cnt) {
        int tok = mylst[slot];
        float av = aff[(size_t)tok * NEXP + e];
#pragma unroll
        for (int nf = 0; nf < 3; ++nf) {
          float g = accg[mf][nf][r], uu = accu[mf][nf][r];
          float hv = (g / (1.f + __expf(-g))) * uu * av;
          int col = n0 + nsub + nf * 16 + l15;
          h4[(size_t)(slotbase + slot) * IDIM + col] = f2bf(hv);
        }
      }
    }
}

// ---------------- down GEMM: out[tok] += h4[slot] @ WdT (atomic combine) ----------------
__global__ __launch_bounds__(512) void down_kernel(
    const unsigned short* __restrict__ h4, const unsigned short* __restrict__ wbuf,
    float* __restrict__ out, const int* __restrict__ lst,
    const int* __restrict__ cnts, const int* __restrict__ gbs,
    const int* __restrict__ ess, const int* __restrict__ gtot_g,
    int ge, int G) {
  int e, m0, n0, cnt;
  const int bx = xcd_swz(blockIdx.x, gridDim.x);
  if (!locate(bx, gbs, cnts, ge, G, gtot_g, e, m0, n0, cnt)) return;
  const int j = e - ge;
  const int slotbase = ess[e];
  const unsigned short* wdt = wbuf + (size_t)j * 3 * WEL + 2 * (size_t)WEL;

  __shared__ __align__(16) unsigned short Al[2 * ASZ];   // 64KB
  __shared__ __align__(16) unsigned short Bl[2 * BSZ];   // 24KB

  const int tid = threadIdx.x;
  const int wv = tid >> 6, lane = tid & 63;
  const int msub = (wv >> 1) * 64, nsub = (wv & 1) * 48;
  const int l15 = lane & 15, l4 = lane >> 4;
  const int lr = lane >> 3, lc = lane & 7;
  const int* mylst = lst + e * T_TOK;

  const unsigned short* asrc[4]; unsigned short* adst[4];
#pragma unroll
  for (int u = 0; u < 4; ++u) {
    int s = wv + 8 * u;
    int r = s * 8 + lr;
    int hr = min(m0 + r, cnt - 1);
    asrc[u] = h4 + (size_t)(slotbase + hr) * IDIM + (lc ^ (r & 7)) * 8;
    adst[u] = &Al[s * 512];
  }
  // B: 12 segs; wv takes {wv}, wv<4 also {8+wv}  -> loads: wv<4:6, wv>=4:5
  const unsigned short* bsrc0; unsigned short* bdst0;
  const unsigned short* bsrc1 = nullptr; unsigned short* bdst1 = nullptr;
  {
    int r0 = wv * 8 + lr;
    bsrc0 = wdt + (size_t)(n0 + r0) * IDIM + (size_t)((lc ^ (r0 & 7)) * 8);
    bdst0 = &Bl[wv * 512];
    if (wv < 4) {
      int r1 = (8 + wv) * 8 + lr;
      bsrc1 = wdt + (size_t)(n0 + r1) * IDIM + (size_t)((lc ^ (r1 & 7)) * 8);
      bdst1 = &Bl[(8 + wv) * 512];
    }
  }

  f32x4 acc[4][3];
#pragma unroll
  for (int mf = 0; mf < 4; ++mf)
#pragma unroll
    for (int nf = 0; nf < 3; ++nf) acc[mf][nf] = (f32x4)0.f;

  auto stage = [&](int buf, int k0) {
    int ao = buf * ASZ, bo = buf * BSZ;
#pragma unroll
    for (int u = 0; u < 4; ++u) gload16(asrc[u] + k0, adst[u] + ao);
    gload16(bsrc0 + k0, bdst0 + bo);
    if (wv < 4) gload16(bsrc1 + k0, bdst1 + bo);
  };
  auto waitprev = [&]() {
    if (wv < 4) { asm volatile("s_waitcnt vmcnt(6)" ::: "memory"); }
    else        { asm volatile("s_waitcnt vmcnt(5)" ::: "memory"); }
  };
  auto compute = [&](int buf) {
    const unsigned short* Ab = Al + buf * ASZ;
    const unsigned short* Bb = Bl + buf * BSZ;
#pragma unroll
    for (int kk = 0; kk < 2; ++kk) {
      s16x8 af[4];
#pragma unroll
      for (int mf = 0; mf < 4; ++mf) {
        int R = msub + mf * 16 + l15;
        int sl = (kk * 4 + l4) ^ (R & 7);
        af[mf] = *(const s16x8*)(&Ab[R * 64 + sl * 8]);
      }
#pragma unroll
      for (int nf = 0; nf < 3; ++nf) {
        int R = nsub + nf * 16 + l15;
        int sl = (kk * 4 + l4) ^ (R & 7);
        s16x8 bb = *(const s16x8*)(&Bb[R * 64 + sl * 8]);
#pragma unroll
        for (int mf = 0; mf < 4; ++mf)
          acc[mf][nf] = __builtin_amdgcn_mfma_f32_16x16x32_bf16(af[mf], bb, acc[mf][nf], 0, 0, 0);
      }
    }
  };

  stage(0, 0);
#pragma unroll 1
  for (int t = 0; t < NSTEP - 1; t += 2) {
    stage(1, (t + 1) * BK);
    waitprev();
    __builtin_amdgcn_s_barrier();
    compute(0);
    __builtin_amdgcn_s_barrier();
    stage(0, (t + 2) * BK);
    waitprev();
    __builtin_amdgcn_s_barrier();
    compute(1);
    __builtin_amdgcn_s_barrier();
  }
  asm volatile("s_waitcnt vmcnt(0)" ::: "memory");
  __builtin_amdgcn_s_barrier();
  compute(0);

#pragma unroll
  for (int mf = 0; mf < 4; ++mf)
#pragma unroll
    for (int r = 0; r < 4; ++r) {
      int slot = m0 + msub + mf * 16 + l4 * 4 + r;
      if (slot < cnt) {
        int tok = mylst[slot];
#pragma unroll
        for (int nf = 0; nf < 3; ++nf) {
          int col = n0 + nsub + nf * 16 + l15;
          atomicAdd(out + (size_t)tok * HDIM + col, acc[mf][nf][r]);
        }
      }
    }
}

// ---------------- launcher ----------------
extern "C" void kernel_launch(void* const* d_in, const int* in_sizes, int n_in,
                              void* d_out, int out_size, void* d_ws, size_t ws_size,
                              hipStream_t stream) {
  (void)in_sizes; (void)n_in;
  const float* x  = (const float*)d_in[0];
  const float* rw = (const float*)d_in[1];
  const float* rb = (const float*)d_in[2];
  const float* wg = (const float*)d_in[3];
  const float* wu = (const float*)d_in[4];
  const float* wd = (const float*)d_in[5];
  float* out = (float*)d_out;

  // fixed-offset small buffers
  char* ws = (char*)d_ws;
  float* aff = (float*)ws;                         // 131072 B
  int*   cnt = (int*)(ws + 131072);                // 512 B
  int*   lst = (int*)(ws + 131584);                // 131072 B
  int*   gbs = (int*)(ws + 262656);                // 64 B
  int*   ess = (int*)(ws + 262720);                // 64 B
  int*   gtot = (int*)(ws + 262784);               // 64 B (+pad)
  unsigned short* xb = (unsigned short*)(ws + 263168);   // 23,592,960 B
  const size_t OFF_H4 = 263168 + 23592960ull;

  const size_t WELB = (size_t)WEL * 2;             // bytes per bf16 matrix
  int G = 1;
  {
    size_t need8 = OFF_H4 + (size_t)16384 * IDIM * 2 + 8 * 3 * WELB;
    size_t need2 = OFF_H4 + (size_t)8192  * IDIM * 2 + 2 * 3 * WELB;
    if (ws_size >= need8) G = 8;
    else if (ws_size >= need2) G = 2;
  }
  const size_t h4b = (size_t)((G == 8) ? 16384 : (G == 2 ? 8192 : 4096)) * IDIM * 2;
  unsigned short* h4   = (unsigned short*)(ws + OFF_H4);
  unsigned short* wbuf = (unsigned short*)(ws + OFF_H4 + h4b);

  const int NG = NEXP / G;
  const int NBLK = (T_TOK * TOPK / BM + NEXP) * NPAN;   // 2160, divisible by 8

  hipMemsetAsync(out, 0, (size_t)out_size * sizeof(float), stream);
  hipMemsetAsync(cnt, 0, 512, stream);
  cvt_kernel<<<(T_TOK * HDIM / 8) / 256, 256, 0, stream>>>(x, xb);
  router_kernel<<<T_TOK / 16, 256, 0, stream>>>(x, rw, rb, aff, cnt, lst);
  sched_kernel<<<1, 64, 0, stream>>>(cnt, gbs, ess, gtot, G);

  for (int g = 0; g < NG; ++g) {
    int ge = g * G;
    transpose_group_kernel<<<dim3(45, 45, 3 * G), 256, 0, stream>>>(wg, wu, wd, wbuf, ge);
    gateup_kernel<<<NBLK, 512, 0, stream>>>(
        xb, wbuf, aff, lst, cnt, gbs, ess, gtot + g, h4, ge, G);
    down_kernel<<<NBLK, 512, 0, stream>>>(
        h4, wbuf, out, lst, cnt, gbs, ess, gtot + g, ge, G);
  }
}

// Round 8
// 1400.518 us; speedup vs baseline: 1.1968x; 1.1968x over previous
//
#include <hip/hip_runtime.h>

// ---------------- problem constants ----------------
#define T_TOK 4096      // B*S tokens
#define HDIM  2880
#define IDIM  2880
#define NEXP  8
#define TOPK  4
#define WEL   (2880 * 2880)   // elems per weight matrix

// GEMM tiling: 128x96 block tile, BK=64, 4 waves (2x2) of 64x48 (round-6 proven).
// LDS tiles LINEAR [row][64] bf16 (128B rows), XOR-swizzled on the 16B k-slot:
//   physical_slot = logical_slot ^ (row & 7)
// global_load_lds writes lane l -> base + l*16 (linear); per-lane GLOBAL source
// is pre-swizzled so swizzled reads see logical order (both-sides involution).
// Double-buffered, raw s_barrier + counted vmcnt(7); 80KB LDS -> 2 blocks/CU
// (1 block/CU regressed in round 7: coarse 2-phase schedule needs inter-block overlap).
// NEW vs round 6: bijective XCD-chunked swizzle over the LIVE block count so the
// ~16 consecutive m-blocks sharing a B-panel land on one XCD's L2.
#define BM 128
#define BN 96
#define BK 64
#define NPAN 30         // 2880 / 96 output n-panels
#define ASZ (BM * BK)   // 8192 elems / 16 KB per buffer half
#define BSZ (BN * BK)   // 6144 elems / 12 KB per buffer half
#define NSTEP 45        // 2880 / 64

typedef __attribute__((ext_vector_type(8))) short  s16x8;
typedef __attribute__((ext_vector_type(8))) unsigned short u16x8;
typedef __attribute__((ext_vector_type(4))) float  f32x4;

__device__ __forceinline__ unsigned short f2bf(float f) {
  unsigned int u = __float_as_uint(f);
  u += 0x7FFFu + ((u >> 16) & 1u);
  return (unsigned short)(u >> 16);
}

__device__ __forceinline__ void gload16(const unsigned short* g, unsigned short* l) {
  __builtin_amdgcn_global_load_lds(
      (const __attribute__((address_space(1))) void*)g,
      (__attribute__((address_space(3))) void*)l, 16, 0, 0);
}

// bijective XCD-aware block swizzle (m204) over live count n
__device__ __forceinline__ int xcd_swz(int orig, int n) {
  int q = n >> 3, r = n & 7;
  int x = orig & 7, idx = orig >> 3;
  return (x < r ? x * (q + 1) : r * (q + 1) + (x - r) * q) + idx;
}

// ---------------- x f32 -> bf16 ----------------
__global__ __launch_bounds__(256) void cvt_kernel(const float* __restrict__ x,
                                                  unsigned short* __restrict__ xb) {
  int i = blockIdx.x * 256 + threadIdx.x;
  const f32x4* p = (const f32x4*)x;
  f32x4 a = p[2 * (size_t)i];
  f32x4 b = p[2 * (size_t)i + 1];
  u16x8 o;
  o[0] = f2bf(a[0]); o[1] = f2bf(a[1]); o[2] = f2bf(a[2]); o[3] = f2bf(a[3]);
  o[4] = f2bf(b[0]); o[5] = f2bf(b[1]); o[6] = f2bf(b[2]); o[7] = f2bf(b[3]);
  *(u16x8*)(xb + (size_t)i * 8) = o;
}

// ---------------- weight transpose+convert for a group of G experts ----------------
__global__ __launch_bounds__(256) void transpose_group_kernel(
    const float* __restrict__ wg, const float* __restrict__ wu,
    const float* __restrict__ wd, unsigned short* __restrict__ wbuf, int ge) {
  __shared__ unsigned short st[64][72];
  const int z = blockIdx.z, j = z / 3, m = z % 3;
  const float* src = (m == 0 ? wg : (m == 1 ? wu : wd)) + (size_t)(ge + j) * WEL;
  unsigned short* dst = wbuf + (size_t)(j * 3 + m) * WEL;
  const int k0 = blockIdx.x * 64, n0 = blockIdx.y * 64;
  const int tid = threadIdx.x;
#pragma unroll
  for (int u = 0; u < 4; ++u) {
    int idx = tid + u * 256;
    int kr = idx >> 4;
    int nc = (idx & 15) * 4;
    f32x4 v = *(const f32x4*)(src + (size_t)(k0 + kr) * 2880 + (n0 + nc));
#pragma unroll
    for (int q = 0; q < 4; ++q) st[nc + q][kr] = f2bf(v[q]);
  }
  __syncthreads();
  int n = tid >> 2;
  int kc = (tid & 3) * 16;
  u16x8 a = *(const u16x8*)(&st[n][kc]);
  u16x8 b = *(const u16x8*)(&st[n][kc + 8]);
  unsigned short* po = dst + (size_t)(n0 + n) * 2880 + (k0 + kc);
  *(u16x8*)(po) = a;
  *(u16x8*)(po + 8) = b;
}

// ---------------- router: 4 tokens/wave, butterfly reduce ----------------
__global__ __launch_bounds__(256) void router_kernel(const float* __restrict__ x,
                                                     const float* __restrict__ rw,
                                                     const float* __restrict__ rb,
                                                     float* __restrict__ aff,
                                                     int* __restrict__ cnt,
                                                     int* __restrict__ lst) {
  const int wv = threadIdx.x >> 6, lane = threadIdx.x & 63;
  const int tok0 = (blockIdx.x * 4 + wv) * 4;
  float acc[4][NEXP];
#pragma unroll
  for (int t = 0; t < 4; ++t)
#pragma unroll
    for (int e = 0; e < NEXP; ++e) acc[t][e] = 0.f;

#pragma unroll
  for (int it = 0; it < 12; ++it) {
    int c = it * 64 + lane;
    if (c < 720) {
      f32x4 w4[NEXP];
#pragma unroll
      for (int e = 0; e < NEXP; ++e)
        w4[e] = *(const f32x4*)(rw + (size_t)e * HDIM + c * 4);
#pragma unroll
      for (int t = 0; t < 4; ++t) {
        f32x4 xv = *(const f32x4*)(x + (size_t)(tok0 + t) * HDIM + c * 4);
#pragma unroll
        for (int e = 0; e < NEXP; ++e)
          acc[t][e] += xv[0] * w4[e][0] + xv[1] * w4[e][1] + xv[2] * w4[e][2] + xv[3] * w4[e][3];
      }
    }
  }
#pragma unroll
  for (int t = 0; t < 4; ++t)
#pragma unroll
    for (int e = 0; e < NEXP; ++e) {
#pragma unroll
      for (int m = 32; m; m >>= 1) acc[t][e] += __shfl_xor(acc[t][e], m);
    }
  if (lane < 4) {
    int tok = tok0 + lane;
    float lg[NEXP];
#pragma unroll
    for (int e = 0; e < NEXP; ++e) lg[e] = acc[lane][e] + rb[e];
    bool used[NEXP];
#pragma unroll
    for (int e = 0; e < NEXP; ++e) used[e] = false;
    int bi[TOPK]; float bv[TOPK];
#pragma unroll
    for (int s = 0; s < TOPK; ++s) {
      int best = 0; float vbest = -1e30f;
#pragma unroll
      for (int e = 0; e < NEXP; ++e)
        if (!used[e] && lg[e] > vbest) { vbest = lg[e]; best = e; }
      used[best] = true; bi[s] = best; bv[s] = vbest;
    }
    float mx = bv[0];
    float w[TOPK]; float ssum = 0.f;
#pragma unroll
    for (int s = 0; s < TOPK; ++s) { w[s] = __expf(bv[s] - mx); ssum += w[s]; }
    float o[NEXP];
#pragma unroll
    for (int e = 0; e < NEXP; ++e) o[e] = 0.f;
#pragma unroll
    for (int s = 0; s < TOPK; ++s) o[bi[s]] = w[s] / ssum;
#pragma unroll
    for (int e = 0; e < NEXP; ++e) aff[(size_t)tok * NEXP + e] = o[e];
#pragma unroll
    for (int s = 0; s < TOPK; ++s) {
      int p = atomicAdd(&cnt[bi[s]], 1);
      lst[bi[s] * T_TOK + p] = tok;
    }
  }
}

// ---------------- sched: per-expert block prefixes + slot prefixes ----------------
__global__ void sched_kernel(const int* __restrict__ cnt, int* __restrict__ gbs,
                             int* __restrict__ ess, int* __restrict__ gtot, int G) {
  if (threadIdx.x == 0 && blockIdx.x == 0) {
    int ng = NEXP / G;
    for (int g = 0; g < ng; ++g) {
      int b = 0, s = 0;
      for (int j = 0; j < G; ++j) {
        int e = g * G + j;
        gbs[e] = b; ess[e] = s;
        b += ((cnt[e] + BM - 1) / BM) * NPAN;
        s += cnt[e];
      }
      gtot[g] = b;
    }
  }
}

// locate (expert, m0, n0) from live-swizzled block id; expert-major, n-outer, m-inner
__device__ __forceinline__ bool locate(int orig, const int* gbs, const int* cnts,
                                       int ge, int G, const int* gtot_g,
                                       int& e, int& m0, int& n0, int& cnt) {
  int gt = *gtot_g;
  if (orig >= gt) return false;
  int bx = xcd_swz(orig, gt);          // bijective within [0, gt)
  int j = 0;
  for (int t = 1; t < G; ++t) j += (bx >= gbs[ge + t]) ? 1 : 0;
  e = ge + j;
  cnt = cnts[e];
  int mb = (cnt + BM - 1) >> 7;
  int local = bx - gbs[e];
  int nIdx = local / mb;
  int mIdx = local - nIdx * mb;
  m0 = mIdx * BM;
  n0 = nIdx * BN;
  return true;
}

// ---------------- gate/up fused GEMM + SwiGLU + affinity -> h4 (per-slot rows) ----------
__global__ __launch_bounds__(256) void gateup_kernel(
    const unsigned short* __restrict__ xb, const unsigned short* __restrict__ wbuf,
    const float* __restrict__ aff, const int* __restrict__ lst,
    const int* __restrict__ cnts, const int* __restrict__ gbs,
    const int* __restrict__ ess, const int* __restrict__ gtot_g,
    unsigned short* __restrict__ h4, int ge, int G) {
  int e, m0, n0, cnt;
  if (!locate(blockIdx.x, gbs, cnts, ge, G, gtot_g, e, m0, n0, cnt)) return;
  const int j = e - ge;
  const int slotbase = ess[e];
  const unsigned short* wgt = wbuf + (size_t)j * 3 * WEL;
  const unsigned short* wut = wgt + WEL;

  __shared__ __align__(16) unsigned short Al[2 * ASZ];    // 32KB dbuf
  __shared__ __align__(16) unsigned short Bgl[2 * BSZ];   // 24KB
  __shared__ __align__(16) unsigned short Bul[2 * BSZ];   // 24KB

  const int tid = threadIdx.x;
  const int wv = tid >> 6, lane = tid & 63;
  const int msub = (wv >> 1) * 64, nsub = (wv & 1) * 48;
  const int l15 = lane & 15, l4 = lane >> 4;
  const int lr = lane >> 3, lc = lane & 7;
  const int* mylst = lst + e * T_TOK;

  const unsigned short* asrc[4]; unsigned short* adst[4];
#pragma unroll
  for (int u = 0; u < 4; ++u) {
    int s = u * 4 + wv;
    int r = s * 8 + lr;
    int tok = mylst[min(m0 + r, cnt - 1)];
    asrc[u] = xb + (size_t)tok * HDIM + (lc ^ (r & 7)) * 8;
    adst[u] = &Al[s * 512];
  }
  const unsigned short* bgsrc[3]; const unsigned short* busrc[3];
  unsigned short* bgdst[3]; unsigned short* budst[3];
#pragma unroll
  for (int u = 0; u < 3; ++u) {
    int s = u * 4 + wv;
    int r = s * 8 + lr;
    size_t off = (size_t)(n0 + r) * HDIM + (size_t)((lc ^ (r & 7)) * 8);
    bgsrc[u] = wgt + off; busrc[u] = wut + off;
    bgdst[u] = &Bgl[s * 512]; budst[u] = &Bul[s * 512];
  }

  f32x4 accg[4][3]; f32x4 accu[4][3];
#pragma unroll
  for (int mf = 0; mf < 4; ++mf)
#pragma unroll
    for (int nf = 0; nf < 3; ++nf) { accg[mf][nf] = (f32x4)0.f; accu[mf][nf] = (f32x4)0.f; }

  auto stage = [&](int buf, int k0) {   // 10 VMEM ops per wave
    int ao = buf * ASZ, bo = buf * BSZ;
#pragma unroll
    for (int u = 0; u < 4; ++u) gload16(asrc[u] + k0, adst[u] + ao);
#pragma unroll
    for (int u = 0; u < 3; ++u) {
      gload16(bgsrc[u] + k0, bgdst[u] + bo);
      gload16(busrc[u] + k0, budst[u] + bo);
    }
  };
  auto compute = [&](int buf) {
    const unsigned short* Ab = Al + buf * ASZ;
    const unsigned short* Bg = Bgl + buf * BSZ;
    const unsigned short* Bu = Bul + buf * BSZ;
#pragma unroll
    for (int kk = 0; kk < 2; ++kk) {
      s16x8 af[4];
#pragma unroll
      for (int mf = 0; mf < 4; ++mf) {
        int R = msub + mf * 16 + l15;
        int sl = (kk * 4 + l4) ^ (R & 7);
        af[mf] = *(const s16x8*)(&Ab[R * 64 + sl * 8]);
      }
#pragma unroll
      for (int nf = 0; nf < 3; ++nf) {
        int R = nsub + nf * 16 + l15;
        int sl = (kk * 4 + l4) ^ (R & 7);
        s16x8 bg = *(const s16x8*)(&Bg[R * 64 + sl * 8]);
        s16x8 bu = *(const s16x8*)(&Bu[R * 64 + sl * 8]);
#pragma unroll
        for (int mf = 0; mf < 4; ++mf) {
          accg[mf][nf] = __builtin_amdgcn_mfma_f32_16x16x32_bf16(af[mf], bg, accg[mf][nf], 0, 0, 0);
          accu[mf][nf] = __builtin_amdgcn_mfma_f32_16x16x32_bf16(af[mf], bu, accu[mf][nf], 0, 0, 0);
        }
      }
    }
  };

  // counted-vmcnt double-buffered pipeline (vmcnt(10) = prev-tile loads done)
  stage(0, 0);
#pragma unroll 1
  for (int t = 0; t < NSTEP - 1; t += 2) {
    stage(1, (t + 1) * BK);
    asm volatile("s_waitcnt vmcnt(10)" ::: "memory");
    __builtin_amdgcn_s_barrier();
    compute(0);
    __builtin_amdgcn_s_barrier();
    stage(0, (t + 2) * BK);
    asm volatile("s_waitcnt vmcnt(10)" ::: "memory");
    __builtin_amdgcn_s_barrier();
    compute(1);
    __builtin_amdgcn_s_barrier();
  }
  asm volatile("s_waitcnt vmcnt(0)" ::: "memory");
  __builtin_amdgcn_s_barrier();
  compute(0);   // tile 44 lives in buf 0

#pragma unroll
  for (int mf = 0; mf < 4; ++mf)
#pragma unroll
    for (int r = 0; r < 4; ++r) {
      int slot = m0 + msub + mf * 16 + l4 * 4 + r;
      if (slot < cnt) {
        int tok = mylst[slot];
        float av = aff[(size_t)tok * NEXP + e];
#pragma unroll
        for (int nf = 0; nf < 3; ++nf) {
          float g = accg[mf][nf][r], uu = accu[mf][nf][r];
          float hv = (g / (1.f + __expf(-g))) * uu * av;
          int col = n0 + nsub + nf * 16 + l15;
          h4[(size_t)(slotbase + slot) * IDIM + col] = f2bf(hv);
        }
      }
    }
}

// ---------------- down GEMM: out[tok] += h4[slot] @ WdT (atomic combine) ----------------
__global__ __launch_bounds__(256) void down_kernel(
    const unsigned short* __restrict__ h4, const unsigned short* __restrict__ wbuf,
    float* __restrict__ out, const int* __restrict__ lst,
    const int* __restrict__ cnts, const int* __restrict__ gbs,
    const int* __restrict__ ess, const int* __restrict__ gtot_g,
    int ge, int G) {
  int e, m0, n0, cnt;
  if (!locate(blockIdx.x, gbs, cnts, ge, G, gtot_g, e, m0, n0, cnt)) return;
  const int j = e - ge;
  const int slotbase = ess[e];
  const unsigned short* wdt = wbuf + (size_t)j * 3 * WEL + 2 * (size_t)WEL;

  __shared__ __align__(16) unsigned short Al[2 * ASZ];   // 32KB
  __shared__ __align__(16) unsigned short Bl[2 * BSZ];   // 24KB

  const int tid = threadIdx.x;
  const int wv = tid >> 6, lane = tid & 63;
  const int msub = (wv >> 1) * 64, nsub = (wv & 1) * 48;
  const int l15 = lane & 15, l4 = lane >> 4;
  const int lr = lane >> 3, lc = lane & 7;
  const int* mylst = lst + e * T_TOK;

  const unsigned short* asrc[4]; unsigned short* adst[4];
#pragma unroll
  for (int u = 0; u < 4; ++u) {
    int s = u * 4 + wv;
    int r = s * 8 + lr;
    int hr = min(m0 + r, cnt - 1);
    asrc[u] = h4 + (size_t)(slotbase + hr) * IDIM + (lc ^ (r & 7)) * 8;
    adst[u] = &Al[s * 512];
  }
  const unsigned short* bsrc[3]; unsigned short* bdst[3];
#pragma unroll
  for (int u = 0; u < 3; ++u) {
    int s = u * 4 + wv;
    int r = s * 8 + lr;
    bsrc[u] = wdt + (size_t)(n0 + r) * IDIM + (size_t)((lc ^ (r & 7)) * 8);
    bdst[u] = &Bl[s * 512];
  }

  f32x4 acc[4][3];
#pragma unroll
  for (int mf = 0; mf < 4; ++mf)
#pragma unroll
    for (int nf = 0; nf < 3; ++nf) acc[mf][nf] = (f32x4)0.f;

  auto stage = [&](int buf, int k0) {   // 7 VMEM ops per wave
    int ao = buf * ASZ, bo = buf * BSZ;
#pragma unroll
    for (int u = 0; u < 4; ++u) gload16(asrc[u] + k0, adst[u] + ao);
#pragma unroll
    for (int u = 0; u < 3; ++u) gload16(bsrc[u] + k0, bdst[u] + bo);
  };
  auto compute = [&](int buf) {
    const unsigned short* Ab = Al + buf * ASZ;
    const unsigned short* Bb = Bl + buf * BSZ;
#pragma unroll
    for (int kk = 0; kk < 2; ++kk) {
      s16x8 af[4];
#pragma unroll
      for (int mf = 0; mf < 4; ++mf) {
        int R = msub + mf * 16 + l15;
        int sl = (kk * 4 + l4) ^ (R & 7);
        af[mf] = *(const s16x8*)(&Ab[R * 64 + sl * 8]);
      }
#pragma unroll
      for (int nf = 0; nf < 3; ++nf) {
        int R = nsub + nf * 16 + l15;
        int sl = (kk * 4 + l4) ^ (R & 7);
        s16x8 bb = *(const s16x8*)(&Bb[R * 64 + sl * 8]);
#pragma unroll
        for (int mf = 0; mf < 4; ++mf)
          acc[mf][nf] = __builtin_amdgcn_mfma_f32_16x16x32_bf16(af[mf], bb, acc[mf][nf], 0, 0, 0);
      }
    }
  };

  stage(0, 0);
#pragma unroll 1
  for (int t = 0; t < NSTEP - 1; t += 2) {
    stage(1, (t + 1) * BK);
    asm volatile("s_waitcnt vmcnt(7)" ::: "memory");
    __builtin_amdgcn_s_barrier();
    compute(0);
    __builtin_amdgcn_s_barrier();
    stage(0, (t + 2) * BK);
    asm volatile("s_waitcnt vmcnt(7)" ::: "memory");
    __builtin_amdgcn_s_barrier();
    compute(1);
    __builtin_amdgcn_s_barrier();
  }
  asm volatile("s_waitcnt vmcnt(0)" ::: "memory");
  __builtin_amdgcn_s_barrier();
  compute(0);

#pragma unroll
  for (int mf = 0; mf < 4; ++mf)
#pragma unroll
    for (int r = 0; r < 4; ++r) {
      int slot = m0 + msub + mf * 16 + l4 * 4 + r;
      if (slot < cnt) {
        int tok = mylst[slot];
#pragma unroll
        for (int nf = 0; nf < 3; ++nf) {
          int col = n0 + nsub + nf * 16 + l15;
          atomicAdd(out + (size_t)tok * HDIM + col, acc[mf][nf][r]);
        }
      }
    }
}

// ---------------- launcher ----------------
extern "C" void kernel_launch(void* const* d_in, const int* in_sizes, int n_in,
                              void* d_out, int out_size, void* d_ws, size_t ws_size,
                              hipStream_t stream) {
  (void)in_sizes; (void)n_in;
  const float* x  = (const float*)d_in[0];
  const float* rw = (const float*)d_in[1];
  const float* rb = (const float*)d_in[2];
  const float* wg = (const float*)d_in[3];
  const float* wu = (const float*)d_in[4];
  const float* wd = (const float*)d_in[5];
  float* out = (float*)d_out;

  // fixed-offset small buffers
  char* ws = (char*)d_ws;
  float* aff = (float*)ws;                         // 131072 B
  int*   cnt = (int*)(ws + 131072);                // 512 B
  int*   lst = (int*)(ws + 131584);                // 131072 B
  int*   gbs = (int*)(ws + 262656);                // 64 B
  int*   ess = (int*)(ws + 262720);                // 64 B
  int*   gtot = (int*)(ws + 262784);               // 64 B (+pad)
  unsigned short* xb = (unsigned short*)(ws + 263168);   // 23,592,960 B
  const size_t OFF_H4 = 263168 + 23592960ull;

  const size_t WELB = (size_t)WEL * 2;             // bytes per bf16 matrix
  int G = 1;
  {
    size_t need8 = OFF_H4 + (size_t)16384 * IDIM * 2 + 8 * 3 * WELB;
    size_t need2 = OFF_H4 + (size_t)8192  * IDIM * 2 + 2 * 3 * WELB;
    if (ws_size >= need8) G = 8;
    else if (ws_size >= need2) G = 2;
  }
  const size_t h4b = (size_t)((G == 8) ? 16384 : (G == 2 ? 8192 : 4096)) * IDIM * 2;
  unsigned short* h4   = (unsigned short*)(ws + OFF_H4);
  unsigned short* wbuf = (unsigned short*)(ws + OFF_H4 + h4b);

  const int NG = NEXP / G;
  const int NBLK = (T_TOK * TOPK / BM + NEXP) * NPAN;   // 4080 worst-case

  hipMemsetAsync(out, 0, (size_t)out_size * sizeof(float), stream);
  hipMemsetAsync(cnt, 0, 512, stream);
  cvt_kernel<<<(T_TOK * HDIM / 8) / 256, 256, 0, stream>>>(x, xb);
  router_kernel<<<T_TOK / 16, 256, 0, stream>>>(x, rw, rb, aff, cnt, lst);
  sched_kernel<<<1, 64, 0, stream>>>(cnt, gbs, ess, gtot, G);

  for (int g = 0; g < NG; ++g) {
    int ge = g * G;
    transpose_group_kernel<<<dim3(45, 45, 3 * G), 256, 0, stream>>>(wg, wu, wd, wbuf, ge);
    gateup_kernel<<<NBLK, 256, 0, stream>>>(
        xb, wbuf, aff, lst, cnt, gbs, ess, gtot + g, h4, ge, G);
    down_kernel<<<NBLK, 256, 0, stream>>>(
        h4, wbuf, out, lst, cnt, gbs, ess, gtot + g, ge, G);
  }
}